// Round 12
// baseline (66.696 us; speedup 1.0000x reference)
//
#include <hip/hip_runtime.h>

typedef unsigned short u16;
typedef _Float16 f16x8 __attribute__((ext_vector_type(8)));
typedef float f32x4 __attribute__((ext_vector_type(4)));

#define AS1 __attribute__((address_space(1)))
#define AS3 __attribute__((address_space(3)))

// B=16, C=512, N=1024 (H=W=32)
#define BB 16
#define CC 512
#define NN 1024

__device__ __forceinline__ void async16(void* lds, const void* g) {
  __builtin_amdgcn_global_load_lds((AS1 void*)g, (AS3 void*)lds, 16, 0, 0);
}

__device__ __forceinline__ u16 f2h(float f) {
  _Float16 h = (_Float16)f;  // v_cvt_f16_f32, RTE
  return __builtin_bit_cast(u16, h);
}
__device__ __forceinline__ float h2f(u16 u) {
  return (float)__builtin_bit_cast(_Float16, u);
}

// Stage a ROWS x 64-col fp16 tile with T threads: LDS dest linear
// (global_load_lds constraint), global SOURCE pre-swizzled so a ds_read with
// col8^(row&7) lands on the right data (T2 / m173 pattern).
template <int ROWS, int T>
__device__ __forceinline__ void stageT(u16* lds, const u16* src, size_t ld, int t) {
#pragma unroll
  for (int i = 0; i < ROWS * 8 / T; ++i) {
    int f = i * T + t;
    int row = f >> 3;                // 0..ROWS-1
    int c8 = f & 7;                  // 16B slot within row
    int sc = (c8 ^ (row & 7)) * 8;   // swizzled source column (elems)
    async16(&lds[(size_t)f * 8], src + (size_t)row * ld + sc);
  }
}

// Read 8 contiguous logical k-elements [k0,k0+8) of `row` from swizzled tile.
__device__ __forceinline__ f16x8 ldsfrag(const u16* lds, int row, int k0) {
  return *(const f16x8*)&lds[row * 64 + (k0 ^ ((row & 7) * 8))];
}

// ---------- Kernel 1: fused mean + fp16 cast + transpose -------------------
// Writes xh16 = fp16(x) [B,C,N] and xt16 = fp16(x)^T [B,N,C] + row means.
__global__ __launch_bounds__(256) void k_prepT(const float* __restrict__ x,
                                               u16* __restrict__ xh,
                                               u16* __restrict__ xt,
                                               float* __restrict__ mu) {
  int lid = blockIdx.x;                  // 0..255
  int sw = (lid & 7) * 32 + (lid >> 3);  // bijective XCD chunking
  int b = sw >> 4;
  int c0 = (sw & 15) * 32;
  int t = threadIdx.x;
  int row = t >> 3;   // 0..31 (c-local)
  int col4 = t & 7;   // float4 slot base
  __shared__ u16 tr[2][64][40];

  const float* xb = x + ((size_t)b * CC + c0) * NN;
  u16* hb = xh + ((size_t)b * CC + c0) * NN;
  u16* tb = xt + (size_t)b * NN * CC + c0;

  float sum = 0.f;
  int wkey = col4 * 4;
  for (int nt = 0; nt < 16; ++nt) {
    u16(*tbuf)[40] = tr[nt & 1];
#pragma unroll
    for (int s = 0; s < 2; ++s) {
      int cc4 = col4 + 8 * s;  // n-block 0..15
      size_t off = (size_t)row * NN + nt * 64 + cc4 * 4;
      float4 v = *(const float4*)&xb[off];
      sum += v.x + v.y + v.z + v.w;
      ushort4 h;
      h.x = f2h(v.x); h.y = f2h(v.y); h.z = f2h(v.z); h.w = f2h(v.w);
      *(ushort4*)&hb[off] = h;
      int csw = row ^ wkey;
      tbuf[cc4 * 4 + 0][csw] = h.x;
      tbuf[cc4 * 4 + 1][csw] = h.y;
      tbuf[cc4 * 4 + 2][csw] = h.z;
      tbuf[cc4 * 4 + 3][csw] = h.w;
    }
    __syncthreads();
    int np = t >> 2, cs = t & 3;
    int rkey = ((np >> 2) & 7) * 4;
#pragma unroll
    for (int s2 = 0; s2 < 2; ++s2) {
      int cl = cs * 4 + s2 * 16;
      *(ushort4*)&tb[(size_t)(nt * 64 + np) * CC + cl] =
          *(ushort4*)&tbuf[np][cl ^ rkey];
    }
    // buffer nt&1 overwritten at nt+2, after the barrier inside nt+1.
  }
  sum += __shfl_xor(sum, 1, 64);
  sum += __shfl_xor(sum, 2, 64);
  sum += __shfl_xor(sum, 4, 64);
  if ((t & 7) == 0) mu[(size_t)b * CC + c0 + row] = sum * (1.0f / (float)NN);
}

// ---------- Kernel 2: FUSED energy GEMM + dual softmax -> att --------------
// Block = 32 c-rows x all 512 d of one batch (grid 256, 1 blk/CU).
// Energy rows computed fully in registers (64 f32/thread); no E round-trip.
// B-panel = batch's full 512-row xh col-slice (1 MB, L2-resident); A c A ⊂ B
// so A-frags read from the same LDS panel. 2x64KB LDS dbuf, 2-phase.
__global__ __launch_bounds__(256, 1) void k_fused(const u16* __restrict__ xh,
                                                  const float* __restrict__ mu,
                                                  const float* __restrict__ beta_p,
                                                  u16* __restrict__ att) {
  int lid = blockIdx.x;                  // 0..255
  int sw = (lid & 7) * 32 + (lid >> 3);  // XCD chunking: 2 batches/XCD
  int b = sw >> 4;
  int c0 = (sw & 15) * 32;

  __shared__ u16 lds[2 * 32768];  // 2 x 64KB: B-panel [512][64] swizzled
  __shared__ float prA[32][4], prB[32][4];
  int t = threadIdx.x;
  int lane = t & 63, w = t >> 6;
  int wc = w * 128;                // wave's 128-col slice of d
  int fr = lane & 15, fk = (lane >> 4) * 8;

  const u16* Bb = xh + (size_t)b * CC * NN;

  f32x4 acc[2][8];
#pragma unroll
  for (int m = 0; m < 2; ++m)
#pragma unroll
    for (int n = 0; n < 8; ++n) acc[m][n] = (f32x4)(0.0f);

  stageT<512, 256>(lds, Bb, NN, t);
  __syncthreads();

  int cur = 0;
  for (int ks = 0; ks < NN; ks += 64) {
    if (ks + 64 < NN) stageT<512, 256>(lds + (cur ^ 1) * 32768, Bb + ks + 64, NN, t);
    const u16* cb = lds + cur * 32768;
#pragma unroll
    for (int kk = 0; kk < 2; ++kk) {
      f16x8 af[2], bg[8];
#pragma unroll
      for (int m = 0; m < 2; ++m) af[m] = ldsfrag(cb, c0 + m * 16 + fr, kk * 32 + fk);
#pragma unroll
      for (int n = 0; n < 8; ++n) bg[n] = ldsfrag(cb, wc + n * 16 + fr, kk * 32 + fk);
#pragma unroll
      for (int m = 0; m < 2; ++m)
#pragma unroll
        for (int n = 0; n < 8; ++n)
          acc[m][n] = __builtin_amdgcn_mfma_f32_16x16x32_f16(af[m], bg[n], acc[m][n], 0, 0, 0);
    }
    __syncthreads();  // drains next-tile loads (vmcnt 0) + barrier
    cur ^= 1;
  }

  // ---- softmax phase (C/D layout: row=(lane>>4)*4+q, col=lane&15) ----
  const float* mub = mu + (size_t)b * CC;
  float bta = *beta_p;
  float muc_l[2][4], mud_l[8];
#pragma unroll
  for (int m = 0; m < 2; ++m)
#pragma unroll
    for (int q = 0; q < 4; ++q)
      muc_l[m][q] = mub[c0 + m * 16 + (lane >> 4) * 4 + q];
#pragma unroll
  for (int n = 0; n < 8; ++n) mud_l[n] = mub[wc + n * 16 + fr];

  // pass 1: per-row min(e) and max(sigma)
  float eminr[2][4], smaxr[2][4];
#pragma unroll
  for (int m = 0; m < 2; ++m)
#pragma unroll
    for (int q = 0; q < 4; ++q) {
      float emin_p = 3.4e38f, smax_p = -3.4e38f;
#pragma unroll
      for (int n = 0; n < 8; ++n) {
        float e = acc[m][n][q];
        emin_p = fminf(emin_p, e);
        float sg = (e - 1024.f * muc_l[m][q] * mud_l[n]) * (1.0f / 32768.0f);
        smax_p = fmaxf(smax_p, sg);
      }
#pragma unroll
      for (int msk = 1; msk <= 8; msk <<= 1) {
        emin_p = fminf(emin_p, __shfl_xor(emin_p, msk, 64));
        smax_p = fmaxf(smax_p, __shfl_xor(smax_p, msk, 64));
      }
      int r = m * 16 + (lane >> 4) * 4 + q;
      if ((lane & 15) == 0) { prA[r][w] = emin_p; prB[r][w] = smax_p; }
    }
  __syncthreads();
#pragma unroll
  for (int m = 0; m < 2; ++m)
#pragma unroll
    for (int q = 0; q < 4; ++q) {
      int r = m * 16 + (lane >> 4) * 4 + q;
      eminr[m][q] = fminf(fminf(prA[r][0], prA[r][1]), fminf(prA[r][2], prA[r][3]));
      smaxr[m][q] = fmaxf(fmaxf(prB[r][0], prB[r][1]), fmaxf(prB[r][2], prB[r][3]));
    }
  __syncthreads();

  // pass 2: per-row sums
  float wer[2][4], wsr[2][4];
#pragma unroll
  for (int m = 0; m < 2; ++m)
#pragma unroll
    for (int q = 0; q < 4; ++q) {
      float se_p = 0.f, ss_p = 0.f;
#pragma unroll
      for (int n = 0; n < 8; ++n) {
        float e = acc[m][n][q];
        se_p += __expf(eminr[m][q] - e);
        float sg = (e - 1024.f * muc_l[m][q] * mud_l[n]) * (1.0f / 32768.0f);
        ss_p += __expf(sg - smaxr[m][q]);
      }
#pragma unroll
      for (int msk = 1; msk <= 8; msk <<= 1) {
        se_p += __shfl_xor(se_p, msk, 64);
        ss_p += __shfl_xor(ss_p, msk, 64);
      }
      int r = m * 16 + (lane >> 4) * 4 + q;
      if ((lane & 15) == 0) { prA[r][w] = se_p; prB[r][w] = ss_p; }
    }
  __syncthreads();
#pragma unroll
  for (int m = 0; m < 2; ++m)
#pragma unroll
    for (int q = 0; q < 4; ++q) {
      int r = m * 16 + (lane >> 4) * 4 + q;
      float se = prA[r][0] + prA[r][1] + prA[r][2] + prA[r][3];
      float ss = prB[r][0] + prB[r][1] + prB[r][2] + prB[r][3];
      wer[m][q] = (1.0f - bta) / se;
      wsr[m][q] = bta / ss;
    }
  __syncthreads();  // staging LDS now dead; reuse for att tile

  // pass 3: recompute exp, blend, stage att tile in LDS (stride 520)
  u16* at = (u16*)lds;
#pragma unroll
  for (int m = 0; m < 2; ++m)
#pragma unroll
    for (int q = 0; q < 4; ++q) {
      int r = m * 16 + (lane >> 4) * 4 + q;
#pragma unroll
      for (int n = 0; n < 8; ++n) {
        float e = acc[m][n][q];
        float pe = __expf(eminr[m][q] - e);
        float sg = (e - 1024.f * muc_l[m][q] * mud_l[n]) * (1.0f / 32768.0f);
        float ps = __expf(sg - smaxr[m][q]);
        at[r * 520 + wc + n * 16 + fr] = f2h(ps * wsr[m][q] + pe * wer[m][q]);
      }
    }
  __syncthreads();

  // coalesced copy: 32 rows x 512 u16 -> global att
  int row = t >> 3;
  int colb = (t & 7) * 8;
  u16* arow = att + ((size_t)b * CC + c0 + row) * CC;
#pragma unroll
  for (int i = 0; i < 8; ++i) {
    int col = colb + i * 64;
    *(uint4*)&arow[col] = *(const uint4*)&at[row * 520 + col];
  }
}

// ---------- Kernel 3: out = gamma * (att @ X) + fp16(x) --------------------
// NT GEMM: out[c,n] = sum_d att[c,d] * xt[n,d]; residual read from xh (fp16).
__global__ __launch_bounds__(256, 2) void k_gemm2(const u16* __restrict__ att,
                                                  const u16* __restrict__ xt,
                                                  const u16* __restrict__ xh,
                                                  const float* __restrict__ gamma_p,
                                                  float* __restrict__ out) {
  int lid = blockIdx.x;                  // 0..511
  int sw = (lid & 7) * 64 + (lid >> 3);  // XCD chunking: 2 batches/XCD
  int b = sw >> 5;
  int r = sw & 31;
  int by = r >> 3;  // c tile (0..3)
  int bx = r & 7;   // n tile (0..7)

  __shared__ u16 lds[2 * 16384];  // per buf: A[128*64]@0, B[128*64]@8192
  int t = threadIdx.x;
  int lane = t & 63, w = t >> 6;
  int wr = (w >> 1) * 64, wc = (w & 1) * 64;
  int fr = lane & 15, fk = (lane >> 4) * 8;

  const u16* Ab = att + ((size_t)b * CC + by * 128) * CC;
  const u16* Bb = xt + ((size_t)b * NN + bx * 128) * CC;

  f32x4 acc[4][4];
#pragma unroll
  for (int m = 0; m < 4; ++m)
#pragma unroll
    for (int n = 0; n < 4; ++n) acc[m][n] = (f32x4)(0.0f);

  stageT<128, 256>(lds, Ab, CC, t);
  stageT<128, 256>(lds + 8192, Bb, CC, t);
  __syncthreads();

  int cur = 0;
  for (int ks = 0; ks < CC; ks += 64) {
    if (ks + 64 < CC) {
      u16* nb = lds + (cur ^ 1) * 16384;
      stageT<128, 256>(nb, Ab + ks + 64, CC, t);
      stageT<128, 256>(nb + 8192, Bb + ks + 64, CC, t);
    }
    const u16* cb = lds + cur * 16384;
#pragma unroll
    for (int kk = 0; kk < 2; ++kk) {
      f16x8 af[4], bg[4];
#pragma unroll
      for (int m = 0; m < 4; ++m) af[m] = ldsfrag(cb, wr + m * 16 + fr, kk * 32 + fk);
#pragma unroll
      for (int n = 0; n < 4; ++n) bg[n] = ldsfrag(cb + 8192, wc + n * 16 + fr, kk * 32 + fk);
#pragma unroll
      for (int m = 0; m < 4; ++m)
#pragma unroll
        for (int n = 0; n < 4; ++n)
          acc[m][n] = __builtin_amdgcn_mfma_f32_16x16x32_f16(af[m], bg[n], acc[m][n], 0, 0, 0);
    }
    __syncthreads();
    cur ^= 1;
  }

  float g = *gamma_p;
  const u16* xb = xh + ((size_t)b * CC + by * 128) * NN + bx * 128;
  float* ob = out + ((size_t)b * CC + by * 128) * NN + bx * 128;
  int orow = wr + (lane >> 4) * 4;
  int ocol = wc + (lane & 15);
#pragma unroll
  for (int m = 0; m < 4; ++m)
#pragma unroll
    for (int n = 0; n < 4; ++n)
#pragma unroll
      for (int q = 0; q < 4; ++q) {
        size_t rr = (size_t)(orow + m * 16 + q) * NN + ocol + n * 16;
        ob[rr] = g * acc[m][n][q] + h2f(xb[rr]);
      }
}

extern "C" void kernel_launch(void* const* d_in, const int* in_sizes, int n_in,
                              void* d_out, int out_size, void* d_ws, size_t ws_size,
                              hipStream_t stream) {
  const float* x = (const float*)d_in[0];
  const float* gamma = (const float*)d_in[1];
  const float* beta = (const float*)d_in[2];
  float* out = (float*)d_out;

  constexpr size_t BCN = (size_t)BB * CC * NN;  // 8,388,608
  constexpr size_t BCC = (size_t)BB * CC * CC;  // 4,194,304
  u16* xh = (u16*)d_ws;              // 16.78 MB fp16(x) (live through gemm2 residual)
  u16* xt = xh + BCN;                // 16.78 MB fp16(x)^T
  float* mu = (float*)(xt + BCN);    // 32 KB
  u16* att = (u16*)(mu + (size_t)BB * CC);  // 8.39 MB
  // total ws use ~= 42 MB (E eliminated by fusion)

  k_prepT<<<256, 256, 0, stream>>>(x, xh, xt, mu);
  k_fused<<<256, 256, 0, stream>>>(xh, mu, beta, att);
  k_gemm2<<<512, 256, 0, stream>>>(att, xt, xh, gamma, out);
}

// Round 13
// 58.644 us; speedup vs baseline: 1.1373x; 1.1373x over previous
//
#include <hip/hip_runtime.h>

typedef unsigned short u16;
typedef _Float16 f16x8 __attribute__((ext_vector_type(8)));
typedef float f32x4 __attribute__((ext_vector_type(4)));

#define AS1 __attribute__((address_space(1)))
#define AS3 __attribute__((address_space(3)))

// B=16, C=512, N=1024 (H=W=32)
#define BB 16
#define CC 512
#define NN 1024

__device__ __forceinline__ void async16(void* lds, const void* g) {
  __builtin_amdgcn_global_load_lds((AS1 void*)g, (AS3 void*)lds, 16, 0, 0);
}

__device__ __forceinline__ u16 f2h(float f) {
  _Float16 h = (_Float16)f;  // v_cvt_f16_f32, RTE
  return __builtin_bit_cast(u16, h);
}
__device__ __forceinline__ float h2f(u16 u) {
  return (float)__builtin_bit_cast(_Float16, u);
}

__device__ __forceinline__ float wredSum(float v) {
  for (int m = 32; m >= 1; m >>= 1) v += __shfl_xor(v, m, 64);
  return v;
}
__device__ __forceinline__ float wredMin(float v) {
  for (int m = 32; m >= 1; m >>= 1) v = fminf(v, __shfl_xor(v, m, 64));
  return v;
}
__device__ __forceinline__ float wredMax(float v) {
  for (int m = 32; m >= 1; m >>= 1) v = fmaxf(v, __shfl_xor(v, m, 64));
  return v;
}

// Stage a ROWS x 64-col fp16 tile with T threads: LDS dest linear
// (global_load_lds constraint), global SOURCE pre-swizzled so a ds_read with
// col8^(row&7) lands on the right data (T2 / m173 pattern).
template <int ROWS, int T>
__device__ __forceinline__ void stageT(u16* lds, const u16* src, size_t ld, int t) {
#pragma unroll
  for (int i = 0; i < ROWS * 8 / T; ++i) {
    int f = i * T + t;
    int row = f >> 3;                // 0..ROWS-1
    int c8 = f & 7;                  // 16B slot within row
    int sc = (c8 ^ (row & 7)) * 8;   // swizzled source column (elems)
    async16(&lds[(size_t)f * 8], src + (size_t)row * ld + sc);
  }
}

// Read 8 contiguous logical k-elements [k0,k0+8) of `row` from swizzled tile.
__device__ __forceinline__ f16x8 ldsfrag(const u16* lds, int row, int k0) {
  return *(const f16x8*)&lds[row * 64 + (k0 ^ ((row & 7) * 8))];
}

// ---------- Kernel 1: fused mean + fp16 cast + transpose -------------------
// Writes xh16 = fp16(x) [B,C,N] and xt16 = fp16(x)^T [B,N,C] + row means.
__global__ __launch_bounds__(256) void k_prepT(const float* __restrict__ x,
                                               u16* __restrict__ xh,
                                               u16* __restrict__ xt,
                                               float* __restrict__ mu) {
  int lid = blockIdx.x;                  // 0..255
  int sw = (lid & 7) * 32 + (lid >> 3);  // bijective XCD chunking
  int b = sw >> 4;
  int c0 = (sw & 15) * 32;
  int t = threadIdx.x;
  int row = t >> 3;   // 0..31 (c-local)
  int col4 = t & 7;   // float4 slot base
  __shared__ u16 tr[2][64][40];

  const float* xb = x + ((size_t)b * CC + c0) * NN;
  u16* hb = xh + ((size_t)b * CC + c0) * NN;
  u16* tb = xt + (size_t)b * NN * CC + c0;

  float sum = 0.f;
  int wkey = col4 * 4;
  for (int nt = 0; nt < 16; ++nt) {
    u16(*tbuf)[40] = tr[nt & 1];
#pragma unroll
    for (int s = 0; s < 2; ++s) {
      int cc4 = col4 + 8 * s;  // n-block 0..15
      size_t off = (size_t)row * NN + nt * 64 + cc4 * 4;
      float4 v = *(const float4*)&xb[off];
      sum += v.x + v.y + v.z + v.w;
      ushort4 h;
      h.x = f2h(v.x); h.y = f2h(v.y); h.z = f2h(v.z); h.w = f2h(v.w);
      *(ushort4*)&hb[off] = h;
      int csw = row ^ wkey;
      tbuf[cc4 * 4 + 0][csw] = h.x;
      tbuf[cc4 * 4 + 1][csw] = h.y;
      tbuf[cc4 * 4 + 2][csw] = h.z;
      tbuf[cc4 * 4 + 3][csw] = h.w;
    }
    __syncthreads();
    int np = t >> 2, cs = t & 3;
    int rkey = ((np >> 2) & 7) * 4;
#pragma unroll
    for (int s2 = 0; s2 < 2; ++s2) {
      int cl = cs * 4 + s2 * 16;
      *(ushort4*)&tb[(size_t)(nt * 64 + np) * CC + cl] =
          *(ushort4*)&tbuf[np][cl ^ rkey];
    }
    // buffer nt&1 overwritten at nt+2, after the barrier inside nt+1.
  }
  sum += __shfl_xor(sum, 1, 64);
  sum += __shfl_xor(sum, 2, 64);
  sum += __shfl_xor(sum, 4, 64);
  if ((t & 7) == 0) mu[(size_t)b * CC + c0 + row] = sum * (1.0f / (float)NN);
}

// ---------- Kernel 2: E[kh] = H16 * H16^T over K-half kh (E in fp16) -------
// Split-K x2: 512 blocks (2/CU co-resident), each 128x128 tile x K=512
// (8 steps). E = E[0] + E[1] summed in k_att. 64 KB dbuf, 2-phase.
__global__ __launch_bounds__(256, 2) void k_gemm1(const u16* __restrict__ xh,
                                                  u16* __restrict__ E) {
  int lid = blockIdx.x;                  // 0..511
  int sw = (lid & 7) * 64 + (lid >> 3);  // XCD chunking: 2 batches/XCD
  int b = sw >> 5;
  int rem = sw & 31;
  int kh = rem >> 4;       // K-half (0,1)
  int r = rem & 15;
  int by = r >> 2;  // c tile (0..3)
  int bx = r & 3;   // d tile (0..3)

  __shared__ u16 lds[2 * 16384];  // per buf: A[128*64]@0, B[128*64]@8192
  int t = threadIdx.x;
  int lane = t & 63, w = t >> 6;
  int wr = (w >> 1) * 64, wc = (w & 1) * 64;
  int fr = lane & 15, fk = (lane >> 4) * 8;

  const u16* Ab = xh + ((size_t)b * CC + by * 128) * NN + kh * 512;
  const u16* Bb = xh + ((size_t)b * CC + bx * 128) * NN + kh * 512;

  f32x4 acc[4][4];
#pragma unroll
  for (int m = 0; m < 4; ++m)
#pragma unroll
    for (int n = 0; n < 4; ++n) acc[m][n] = (f32x4)(0.0f);

  stageT<128, 256>(lds, Ab, NN, t);
  stageT<128, 256>(lds + 8192, Bb, NN, t);
  __syncthreads();

  int cur = 0;
  for (int ks = 0; ks < 512; ks += 64) {
    if (ks + 64 < 512) {
      u16* nb = lds + (cur ^ 1) * 16384;
      stageT<128, 256>(nb, Ab + ks + 64, NN, t);
      stageT<128, 256>(nb + 8192, Bb + ks + 64, NN, t);
    }
    const u16* cb = lds + cur * 16384;
#pragma unroll
    for (int kk = 0; kk < 2; ++kk) {
      f16x8 af[4], bg[4];
#pragma unroll
      for (int m = 0; m < 4; ++m) af[m] = ldsfrag(cb, wr + m * 16 + fr, kk * 32 + fk);
#pragma unroll
      for (int n = 0; n < 4; ++n) bg[n] = ldsfrag(cb + 8192, wc + n * 16 + fr, kk * 32 + fk);
#pragma unroll
      for (int m = 0; m < 4; ++m)
#pragma unroll
        for (int n = 0; n < 4; ++n)
          acc[m][n] = __builtin_amdgcn_mfma_f32_16x16x32_f16(af[m], bg[n], acc[m][n], 0, 0, 0);
    }
    __syncthreads();  // drains next-tile loads (vmcnt 0) + barrier
    cur ^= 1;
  }

  u16* Eb = E + (size_t)kh * BB * CC * CC +
            ((size_t)b * CC + by * 128) * CC + bx * 128;
  int orow = wr + (lane >> 4) * 4;
  int ocol = wc + (lane & 15);
#pragma unroll
  for (int m = 0; m < 4; ++m)
#pragma unroll
    for (int n = 0; n < 4; ++n)
#pragma unroll
      for (int q = 0; q < 4; ++q)
        Eb[(size_t)(orow + m * 16 + q) * CC + ocol + n * 16] = f2h(acc[m][n][q]);
}

// ---------- Kernel 3: dual softmax over symmetric E=E0+E1 (fp16) -> att ----
// E symmetric -> row read only; no LDS, no barrier. 512 blocks = 2/CU.
__global__ __launch_bounds__(256) void k_att(const u16* __restrict__ E,
                                             const float* __restrict__ mu,
                                             const float* __restrict__ beta_p,
                                             u16* __restrict__ att) {
  int lid = blockIdx.x;                  // 0..511
  int sw = (lid & 7) * 64 + (lid >> 3);  // same batch->XCD map as gemm1
  int b = sw >> 5;
  int c0 = (sw & 31) * 16;
  int t = threadIdx.x;
  int lane = t & 63, w = t >> 6;
  const u16* E0b = E + (size_t)b * CC * CC;
  const u16* E1b = E0b + (size_t)BB * CC * CC;
  const float* mub = mu + b * CC;
  float bta = *beta_p;

  for (int i = 0; i < 4; ++i) {
    int c = c0 + w * 4 + i;
    const u16* r0 = E0b + (size_t)c * CC;
    const u16* r1 = E1b + (size_t)c * CC;
    float muc = mub[c];

    float e[8], mud[8];
#pragma unroll
    for (int j = 0; j < 8; ++j) {
      int d = lane + j * 64;
      e[j] = h2f(r0[d]) + h2f(r1[d]);
      mud[j] = mub[d];
    }
    // softmax(energy_new) == exp(emin - e) / sum
    float emin = fminf(fminf(fminf(e[0], e[1]), fminf(e[2], e[3])),
                       fminf(fminf(e[4], e[5]), fminf(e[6], e[7])));
    emin = wredMin(emin);
    float pe[8], sum_e = 0.f;
#pragma unroll
    for (int j = 0; j < 8; ++j) { pe[j] = __expf(emin - e[j]); sum_e += pe[j]; }
    sum_e = wredSum(sum_e);

    // sigma = (e - N*muc*mud) * (1/(N*sqrt(N)))
    float sg[8];
#pragma unroll
    for (int j = 0; j < 8; ++j)
      sg[j] = (e[j] - (float)NN * muc * mud[j]) * (1.0f / 32768.0f);
    float smax = fmaxf(fmaxf(fmaxf(sg[0], sg[1]), fmaxf(sg[2], sg[3])),
                       fmaxf(fmaxf(sg[4], sg[5]), fmaxf(sg[6], sg[7])));
    smax = wredMax(smax);
    float ps[8], sum_s = 0.f;
#pragma unroll
    for (int j = 0; j < 8; ++j) { ps[j] = __expf(sg[j] - smax); sum_s += ps[j]; }
    sum_s = wredSum(sum_s);

    float we = (1.0f - bta) / sum_e;
    float wsc = bta / sum_s;
    u16* arow = att + ((size_t)b * CC + c) * CC;
#pragma unroll
    for (int j = 0; j < 8; ++j)
      arow[lane + j * 64] = f2h(ps[j] * wsc + pe[j] * we);
  }
}

// ---------- Kernel 4: out = gamma * (att @ X) + fp16(x) --------------------
// NT GEMM: out[c,n] = sum_d att[c,d] * xt[n,d]; residual read from xh (fp16,
// |x-fp16(x)| <= 2^-11|x| << current error).
__global__ __launch_bounds__(256, 2) void k_gemm2(const u16* __restrict__ att,
                                                  const u16* __restrict__ xt,
                                                  const u16* __restrict__ xh,
                                                  const float* __restrict__ gamma_p,
                                                  float* __restrict__ out) {
  int lid = blockIdx.x;                  // 0..511
  int sw = (lid & 7) * 64 + (lid >> 3);  // XCD chunking: 2 batches/XCD
  int b = sw >> 5;
  int r = sw & 31;
  int by = r >> 3;  // c tile (0..3)
  int bx = r & 7;   // n tile (0..7)

  __shared__ u16 lds[2 * 16384];  // per buf: A[128*64]@0, B[128*64]@8192
  int t = threadIdx.x;
  int lane = t & 63, w = t >> 6;
  int wr = (w >> 1) * 64, wc = (w & 1) * 64;
  int fr = lane & 15, fk = (lane >> 4) * 8;

  const u16* Ab = att + ((size_t)b * CC + by * 128) * CC;
  const u16* Bb = xt + ((size_t)b * NN + bx * 128) * CC;

  f32x4 acc[4][4];
#pragma unroll
  for (int m = 0; m < 4; ++m)
#pragma unroll
    for (int n = 0; n < 4; ++n) acc[m][n] = (f32x4)(0.0f);

  stageT<128, 256>(lds, Ab, CC, t);
  stageT<128, 256>(lds + 8192, Bb, CC, t);
  __syncthreads();

  int cur = 0;
  for (int ks = 0; ks < CC; ks += 64) {
    if (ks + 64 < CC) {
      u16* nb = lds + (cur ^ 1) * 16384;
      stageT<128, 256>(nb, Ab + ks + 64, CC, t);
      stageT<128, 256>(nb + 8192, Bb + ks + 64, CC, t);
    }
    const u16* cb = lds + cur * 16384;
#pragma unroll
    for (int kk = 0; kk < 2; ++kk) {
      f16x8 af[4], bg[4];
#pragma unroll
      for (int m = 0; m < 4; ++m) af[m] = ldsfrag(cb, wr + m * 16 + fr, kk * 32 + fk);
#pragma unroll
      for (int n = 0; n < 4; ++n) bg[n] = ldsfrag(cb + 8192, wc + n * 16 + fr, kk * 32 + fk);
#pragma unroll
      for (int m = 0; m < 4; ++m)
#pragma unroll
        for (int n = 0; n < 4; ++n)
          acc[m][n] = __builtin_amdgcn_mfma_f32_16x16x32_f16(af[m], bg[n], acc[m][n], 0, 0, 0);
    }
    __syncthreads();
    cur ^= 1;
  }

  float g = *gamma_p;
  const u16* xb = xh + ((size_t)b * CC + by * 128) * NN + bx * 128;
  float* ob = out + ((size_t)b * CC + by * 128) * NN + bx * 128;
  int orow = wr + (lane >> 4) * 4;
  int ocol = wc + (lane & 15);
#pragma unroll
  for (int m = 0; m < 4; ++m)
#pragma unroll
    for (int n = 0; n < 4; ++n)
#pragma unroll
      for (int q = 0; q < 4; ++q) {
        size_t rr = (size_t)(orow + m * 16 + q) * NN + ocol + n * 16;
        ob[rr] = g * acc[m][n][q] + h2f(xb[rr]);
      }
}

extern "C" void kernel_launch(void* const* d_in, const int* in_sizes, int n_in,
                              void* d_out, int out_size, void* d_ws, size_t ws_size,
                              hipStream_t stream) {
  const float* x = (const float*)d_in[0];
  const float* gamma = (const float*)d_in[1];
  const float* beta = (const float*)d_in[2];
  float* out = (float*)d_out;

  constexpr size_t BCN = (size_t)BB * CC * NN;  // 8,388,608
  constexpr size_t BCC = (size_t)BB * CC * CC;  // 4,194,304
  u16* xh = (u16*)d_ws;              // 16.78 MB fp16(x) (live through gemm2 residual)
  u16* xt = xh + BCN;                // 16.78 MB fp16(x)^T
  float* mu = (float*)(xt + BCN);    // 32 KB
  u16* E = (u16*)(mu + (size_t)BB * CC);  // 2 x 8.39 MB fp16 energy K-halves
  u16* att = E + 2 * BCC;            // 8.39 MB
  // total ws use ~= 58.8 MB

  k_prepT<<<256, 256, 0, stream>>>(x, xh, xt, mu);
  k_gemm1<<<512, 256, 0, stream>>>(xh, E);
  k_att<<<512, 256, 0, stream>>>(E, mu, beta, att);
  k_gemm2<<<512, 256, 0, stream>>>(att, xt, xh, gamma, out);
}